// Round 1
// baseline (3356.858 us; speedup 1.0000x reference)
//
#include <hip/hip_runtime.h>
#include <cmath>

// ---------------------------------------------------------------------------
// 2-layer LSTM, T=256 B=64 D=H=1024. fp16 MFMA (fp32 accum) everywhere.
//
// Layouts:
//  packed gate col p = h*4 + g   (g: 0=i,1=j,2=f,3=o ; orig col = g*1024+h)
//  A-pack (M x K):  AP[mt][kt][lane][j] = A[mt*16 + (lane&15)][kt*32 + (lane>>4)*8 + j]
//  B-pack (K x G):  WP[nt][kt][lane][j] = W[kt*32 + (lane>>4)*8 + j][origcol(nt*16 + (lane&15))]
//  MFMA 16x16x32 f16: D[row=(lane>>4)*4+r][col=lane&15]  (verified layouts, guide §3)
// ---------------------------------------------------------------------------

typedef _Float16 half8 __attribute__((ext_vector_type(8)));
typedef float f32x4 __attribute__((ext_vector_type(4)));

constexpr int Tt = 256, Bb = 64, Kd = 1024, Gg = 4096;
constexpr int KT = 32;               // k-tiles (K=1024 / 32)
constexpr size_t MT_ELEMS = (size_t)KT * 64 * 8;  // elems per m-tile of an A-pack = 16384

__device__ __forceinline__ f32x4 zero4() { f32x4 z = {0.f, 0.f, 0.f, 0.f}; return z; }
__device__ __forceinline__ float sigmoidf_(float x) { return 1.f / (1.f + expf(-x)); }

// ---- pack W: fp32 [2048][4096] -> 4 fp16 B-packed halves -------------------
__global__ void pack_w_kernel(const float* __restrict__ W0, const float* __restrict__ W1,
                              _Float16* __restrict__ WP0x, _Float16* __restrict__ WP0h,
                              _Float16* __restrict__ WP1x, _Float16* __restrict__ WP1h) {
    int idx = blockIdx.x * 256 + threadIdx.x;      // [0, 256*32*64)
    int half_id = blockIdx.y;                      // 0:W0x 1:W0h 2:W1x 3:W1h
    const float* src = (half_id < 2) ? W0 : W1;
    int rowoff = (half_id & 1) * 1024;
    _Float16* dst = (half_id == 0) ? WP0x : (half_id == 1) ? WP0h : (half_id == 2) ? WP1x : WP1h;

    int lane = idx & 63;
    int kt = (idx >> 6) & 31;
    int nt = idx >> 11;
    int p = nt * 16 + (lane & 15);
    int col = (p & 3) * 1024 + (p >> 2);
    int kbase = rowoff + kt * 32 + (lane >> 4) * 8;
    half8 v;
#pragma unroll
    for (int j = 0; j < 8; ++j) v[j] = (_Float16)src[(size_t)(kbase + j) * Gg + col];
    *reinterpret_cast<half8*>(dst + (size_t)idx * 8) = v;
    (void)kt;
}

__global__ void pack_bias_kernel(const float* __restrict__ b0, const float* __restrict__ b1,
                                 float* __restrict__ bp0, float* __restrict__ bp1) {
    int idx = blockIdx.x * 256 + threadIdx.x;      // [0, 8192)
    int l = idx >> 12, p = idx & 4095;
    int col = (p & 3) * 1024 + (p >> 2);
    (l ? bp1 : bp0)[p] = (l ? b1 : b0)[col];
}

// ---- pack X: fp32 [16384][1024] -> fp16 A-pack -----------------------------
__global__ void pack_a_kernel(const float* __restrict__ X, _Float16* __restrict__ XP) {
    int idx = blockIdx.x * 256 + threadIdx.x;      // [0, 1024*32*64)
    int lane = idx & 63;
    int kt = (idx >> 6) & 31;
    int mt = idx >> 11;
    int m = mt * 16 + (lane & 15);
    int kbase = kt * 32 + (lane >> 4) * 8;
    const float* srow = X + (size_t)m * Kd + kbase;
    half8 v;
#pragma unroll
    for (int j = 0; j < 8; ++j) v[j] = (_Float16)srow[j];
    *reinterpret_cast<half8*>(XP + (size_t)idx * 8) = v;
}

// ---- big x-part GEMM: Z[m][p] = AP@WP + bias. LDS-free (packed operands). --
// block 256 = 4 waves (2x2), block tile 128x128, wave tile 64x64.
__global__ __launch_bounds__(256) void xgemm_kernel(const _Float16* __restrict__ AP,
                                                    const _Float16* __restrict__ WP,
                                                    const float* __restrict__ bias,
                                                    float* __restrict__ Z) {
    int lane = threadIdx.x & 63, wave = threadIdx.x >> 6;
    int wrow = wave >> 1, wcol = wave & 1;
    int mtb = blockIdx.x * 8 + wrow * 4;
    int ntb = blockIdx.y * 8 + wcol * 4;

    f32x4 acc[4][4];
#pragma unroll
    for (int i = 0; i < 4; ++i)
#pragma unroll
        for (int j = 0; j < 4; ++j) acc[i][j] = zero4();

    for (int kt = 0; kt < KT; ++kt) {
        half8 a[4], b[4];
#pragma unroll
        for (int i = 0; i < 4; ++i)
            a[i] = *reinterpret_cast<const half8*>(AP + (((size_t)(mtb + i) * KT + kt) * 64 + lane) * 8);
#pragma unroll
        for (int j = 0; j < 4; ++j)
            b[j] = *reinterpret_cast<const half8*>(WP + (((size_t)(ntb + j) * KT + kt) * 64 + lane) * 8);
#pragma unroll
        for (int i = 0; i < 4; ++i)
#pragma unroll
            for (int j = 0; j < 4; ++j)
                acc[i][j] = __builtin_amdgcn_mfma_f32_16x16x32_f16(a[i], b[j], acc[i][j], 0, 0, 0);
    }

    int r0 = (lane >> 4) * 4, cc = lane & 15;
#pragma unroll
    for (int j = 0; j < 4; ++j) {
        int p = (ntb + j) * 16 + cc;
        float bs = bias[p];
#pragma unroll
        for (int i = 0; i < 4; ++i) {
            int mbase = (mtb + i) * 16 + r0;
#pragma unroll
            for (int r = 0; r < 4; ++r)
                Z[(size_t)(mbase + r) * Gg + p] = acc[i][j][r] + bs;
        }
    }
}

// ---- fused recurrent step: zh = hprev@Wh ; z = zh + Zx ; gates ; c,h -------
// grid 256 (nt), block 256 = 4 waves; wave w = batch m-tile w; 16 packed cols/wg.
__global__ __launch_bounds__(256) void lstm_step_kernel(const float* __restrict__ ZT,
                                                        const _Float16* __restrict__ hprev,
                                                        const _Float16* __restrict__ WPh,
                                                        float* __restrict__ c,
                                                        _Float16* __restrict__ houtA,
                                                        float* __restrict__ houtF) {
    int lane = threadIdx.x & 63, w = threadIdx.x >> 6;
    int nt = blockIdx.x;

    f32x4 acc = zero4();
    for (int kt = 0; kt < KT; ++kt) {
        half8 a = *reinterpret_cast<const half8*>(hprev + (((size_t)w * KT + kt) * 64 + lane) * 8);
        half8 b = *reinterpret_cast<const half8*>(WPh + (((size_t)nt * KT + kt) * 64 + lane) * 8);
        acc = __builtin_amdgcn_mfma_f32_16x16x32_f16(a, b, acc, 0, 0, 0);
    }

    __shared__ float zs[4][16][17];
    int q = lane >> 4, cc = lane & 15;
#pragma unroll
    for (int r = 0; r < 4; ++r)
        zs[w][q * 4 + r][cc] = acc[r] + ZT[(size_t)(w * 16 + q * 4 + r) * Gg + nt * 16 + cc];
    __syncthreads();

    int bl = lane >> 2, hl = lane & 3;          // 16 batches x 4 h-cols per wave
    float zi = zs[w][bl][hl * 4 + 0];
    float zj = zs[w][bl][hl * 4 + 1];
    float zf = zs[w][bl][hl * 4 + 2];
    float zo = zs[w][bl][hl * 4 + 3];
    int b = w * 16 + bl;
    int hcol = nt * 4 + hl;
    float cold = c[(size_t)b * 1024 + hcol];
    float cn = cold * sigmoidf_(zf + 1.0f) + sigmoidf_(zi) * tanhf(zj);
    float hn = tanhf(cn) * sigmoidf_(zo);
    c[(size_t)b * 1024 + hcol] = cn;
    // write h in A-pack layout for next step / next layer: m=b (mt==w), k=hcol
    houtA[(((size_t)w * KT + (hcol >> 5)) * 64 + ((hcol >> 3) & 3) * 16 + bl) * 8 + (hcol & 7)] = (_Float16)hn;
    if (houtF) houtF[(size_t)b * 1024 + hcol] = hn;
}

// ---------------------------------------------------------------------------
extern "C" void kernel_launch(void* const* d_in, const int* in_sizes, int n_in,
                              void* d_out, int out_size, void* d_ws, size_t ws_size,
                              hipStream_t stream) {
    const float* X  = (const float*)d_in[0];
    const float* W0 = (const float*)d_in[1];
    const float* b0 = (const float*)d_in[2];
    const float* W1 = (const float*)d_in[3];
    const float* b1 = (const float*)d_in[4];
    float* out = (float*)d_out;

    char* ws = (char*)d_ws;
    size_t off = 0;
    auto take = [&](size_t n) -> void* {
        void* r = ws + off;
        off += (n + 255) & ~(size_t)255;
        return r;
    };

    const size_t WPB = (size_t)Kd * Gg * 2;            // 8 MiB per packed W half
    _Float16* WP0x = (_Float16*)take(WPB);
    _Float16* WP0h = (_Float16*)take(WPB);
    _Float16* WP1x = (_Float16*)take(WPB);
    _Float16* WP1h = (_Float16*)take(WPB);
    float* bp0 = (float*)take(Gg * 4);
    float* bp1 = (float*)take(Gg * 4);
    const size_t APB = (size_t)Tt * Bb * Kd * 2;       // 32 MiB
    _Float16* XP  = (_Float16*)take(APB);
    _Float16* H1P = (_Float16*)take(APB);
    _Float16* hzero = (_Float16*)take((size_t)Bb * 1024 * 2);       // 128 KiB
    _Float16* h2A   = (_Float16*)take((size_t)2 * Bb * 1024 * 2);   // double buffer
    float* c0 = (float*)take((size_t)Bb * 1024 * 4);
    float* c1 = (float*)take((size_t)Bb * 1024 * 4);

    int Tc = 256;   // Z-chunk timesteps, shrink to fit workspace
    while (Tc > 8 && off + (size_t)Tc * Bb * Gg * 4 > ws_size) Tc >>= 1;
    float* Z = (float*)take((size_t)Tc * Bb * Gg * 4);

    hipMemsetAsync(hzero, 0, (size_t)Bb * 1024 * 2, stream);
    hipMemsetAsync(h2A, 0, (size_t)2 * Bb * 1024 * 2, stream);
    hipMemsetAsync(c0, 0, (size_t)Bb * 1024 * 4, stream);
    hipMemsetAsync(c1, 0, (size_t)Bb * 1024 * 4, stream);

    pack_w_kernel<<<dim3(2048, 4), 256, 0, stream>>>(W0, W1, WP0x, WP0h, WP1x, WP1h);
    pack_bias_kernel<<<32, 256, 0, stream>>>(b0, b1, bp0, bp1);
    pack_a_kernel<<<8192, 256, 0, stream>>>(X, XP);

    const size_t hstep = 4 * MT_ELEMS;   // A-pack elems per timestep (4 m-tiles)

    // ---- layer 0 ----
    for (int t0 = 0; t0 < Tt; t0 += Tc) {
        xgemm_kernel<<<dim3(Tc * Bb / 128, Gg / 128), 256, 0, stream>>>(
            XP + (size_t)t0 * hstep / 16 * 16, WP0x, bp0, Z);
        for (int t = t0; t < t0 + Tc; ++t) {
            const _Float16* hp = (t == 0) ? hzero : H1P + (size_t)(t - 1) * hstep;
            lstm_step_kernel<<<256, 256, 0, stream>>>(
                Z + (size_t)(t - t0) * Bb * Gg, hp, WP0h, c0,
                H1P + (size_t)t * hstep, nullptr);
        }
    }
    // ---- layer 1 ----
    for (int t0 = 0; t0 < Tt; t0 += Tc) {
        xgemm_kernel<<<dim3(Tc * Bb / 128, Gg / 128), 256, 0, stream>>>(
            H1P + (size_t)t0 * hstep, WP1x, bp1, Z);
        for (int t = t0; t < t0 + Tc; ++t) {
            const _Float16* hp = h2A + (size_t)(t & 1) * Bb * 1024;   // buf0 zeroed for t=0
            _Float16* hw = h2A + (size_t)((t + 1) & 1) * Bb * 1024;
            lstm_step_kernel<<<256, 256, 0, stream>>>(
                Z + (size_t)(t - t0) * Bb * Gg, hp, WP1h, c1,
                hw, out + (size_t)t * Bb * 1024);
        }
    }
    (void)in_sizes; (void)n_in; (void)out_size;
}